// Round 6
// baseline (205.544 us; speedup 1.0000x reference)
//
#include <hip/hip_runtime.h>

#define T_TOK 16
#define K_TOP 8
#define NEXP  64
#define DHID  2048
#define FINT  1024

typedef unsigned int   uint_t;
typedef unsigned short ushort_t;
typedef float f32x4 __attribute__((ext_vector_type(4)));

// workspace layout (bytes)
#define ROUTE_OFF 0u
#define AIDX_OFF  4096u
#define NA_OFF    (AIDX_OFF + 256u)
#define XT_OFF    8192u                            // 2048*16 fp32 = 128 KB
#define HPART_OFF 262144u                          // 4*64*1024*16 bf16 = 8 MB
#define HPART_STRIDE ((size_t)NEXP * FINT * T_TOK) // ushorts per dr-slice
#define ABUF_OFF  (HPART_OFF + 8388608u)           // 64*1024*16 bf16 = 2 MB
#define OPART_OFF (ABUF_OFF + 2097152u)            // 64*4*16*2048 bf16 = 16 MB

__device__ __forceinline__ ushort_t f2bf(float f) {
    uint_t u = __builtin_bit_cast(uint_t, f);
    u += 0x7FFFu + ((u >> 16) & 1u);   // RNE
    return (ushort_t)(u >> 16);
}
__device__ __forceinline__ uint_t pk2(float lo, float hi) {
    return (uint_t)f2bf(lo) | ((uint_t)f2bf(hi) << 16);
}
__device__ __forceinline__ float bf_lo(uint_t v) { return __builtin_bit_cast(float, v << 16); }
__device__ __forceinline__ float bf_hi(uint_t v) { return __builtin_bit_cast(float, v & 0xFFFF0000u); }

// ---------------------------------------------------------------------------
// K1: x transpose [T][D]->[D][T] (all 32 blocks) + route/aidx/nA (block 0).
// ---------------------------------------------------------------------------
__global__ void k_prep(const float* __restrict__ x, const int* __restrict__ idx,
                       const float* __restrict__ w, float* __restrict__ xT,
                       float* __restrict__ route, int* __restrict__ aidx,
                       int* __restrict__ nA) {
    const int tid = threadIdx.x;                 // 256
    const int d = blockIdx.x * 64 + (tid & 63);
    const int tq = tid >> 6;
    float4 v;
    v.x = x[(tq * 4 + 0) * DHID + d];
    v.y = x[(tq * 4 + 1) * DHID + d];
    v.z = x[(tq * 4 + 2) * DHID + d];
    v.w = x[(tq * 4 + 3) * DHID + d];
    *reinterpret_cast<float4*>(xT + d * T_TOK + tq * 4) = v;

    if (blockIdx.x != 0) return;
    __shared__ float r[NEXP * T_TOK];
    __shared__ int is64_s;
    if (tid == 0) {
        int allz = 1;
        for (int i = 1; i < 128; i += 2) allz &= (idx[i] == 0);
        is64_s = allz;
    }
    __syncthreads();
    const int is64 = is64_s;
    for (int i = tid; i < NEXP * T_TOK; i += 256) {
        const int e = i >> 4, t = i & 15;
        float s = 0.f;
#pragma unroll
        for (int k = 0; k < K_TOP; ++k) {
            const int flat = t * K_TOP + k;
            const int ev = is64 ? idx[2 * flat] : idx[flat];
            if (ev == e) s += w[flat];
        }
        r[i] = s;
        route[i] = s;
    }
    __syncthreads();
    if (tid == 0) {
        int n = 0;
        for (int e = 0; e < NEXP; ++e) {
            float s = 0.f;
            for (int t = 0; t < T_TOK; ++t) s += r[e * T_TOK + t];
            if (s != 0.f) aidx[n++] = e;
        }
        *nA = n;
    }
}

// ---- shared inner-loop machinery ------------------------------------------
#define FMA4(t, xs)                              \
    acc0[t] = fmaf((xs), w4.x, acc0[t]);         \
    acc1[t] = fmaf((xs), w4.y, acc1[t]);         \
    acc2[t] = fmaf((xs), w4.z, acc2[t]);         \
    acc3[t] = fmaf((xs), w4.w, acc3[t]);
#define FMA_PAIR(u, t0_)                                        \
    { const float xl = bf_lo(u), xh = bf_hi(u);                 \
      FMA4(t0_, xl) FMA4((t0_) + 1, xh) }
#define STEP(jj, B)                                                         \
    { const uint4 q0 = xqw[(jj) * 2]; const uint4 q1 = xqw[(jj) * 2 + 1];   \
      const f32x4 w4 = (B);                                                 \
      FMA_PAIR(q0.x, 0) FMA_PAIR(q0.y, 2) FMA_PAIR(q0.z, 4) FMA_PAIR(q0.w, 6) \
      FMA_PAIR(q1.x, 8) FMA_PAIR(q1.y, 10) FMA_PAIR(q1.z, 12) FMA_PAIR(q1.w, 14) }
#define LDW(j) __builtin_nontemporal_load(wrow + (size_t)(j) * WSTEP)

// bf16 reduction region = 2048 uints (8 KB): layout [j(4)][tp(8)][lane(64)]
#define RW(reg)                                                         \
    { uint_t* p = lds_u + (reg) * 2048 + lane;                          \
      _Pragma("unroll") for (int tp = 0; tp < 8; ++tp) {                \
          p[(0 * 8 + tp) * 64] = pk2(acc0[2 * tp], acc0[2 * tp + 1]);   \
          p[(1 * 8 + tp) * 64] = pk2(acc1[2 * tp], acc1[2 * tp + 1]);   \
          p[(2 * 8 + tp) * 64] = pk2(acc2[2 * tp], acc2[2 * tp + 1]);   \
          p[(3 * 8 + tp) * 64] = pk2(acc3[2 * tp], acc3[2 * tp + 1]); } }
#define RR(reg)                                                         \
    { const uint_t* p = lds_u + (reg) * 2048 + lane;                    \
      _Pragma("unroll") for (int tp = 0; tp < 8; ++tp) {                \
          uint_t u;                                                     \
          u = p[(0 * 8 + tp) * 64]; acc0[2 * tp] += bf_lo(u); acc0[2 * tp + 1] += bf_hi(u); \
          u = p[(1 * 8 + tp) * 64]; acc1[2 * tp] += bf_lo(u); acc1[2 * tp + 1] += bf_hi(u); \
          u = p[(2 * 8 + tp) * 64]; acc2[2 * tp] += bf_lo(u); acc2[2 * tp + 1] += bf_hi(u); \
          u = p[(3 * 8 + tp) * 64]; acc3[2 * tp] += bf_lo(u); acc3[2 * tp + 1] += bf_hi(u); } }

// ---------------------------------------------------------------------------
// K2: up-proj partials. Block=(active e, d-range dr of 512 rows) -> reads a
// CONTIGUOUS 2 MB weight slab. Waves (dsub=wid>>2, fq=wid&3): rows
// [dr*512+dsub*128,+128), f-quarter fq (lane owns 4 f). 4->1 dsub tree.
// h_part[dr][e][f][t] (bf16) = sum_{d in dr} x[t][d]*Wu[e][d][f]
// ---------------------------------------------------------------------------
__global__ __launch_bounds__(1024, 4) void k_up(
    const float* __restrict__ xT, const float* __restrict__ Wu,
    const int* __restrict__ aidx, const int* __restrict__ nAp,
    ushort_t* __restrict__ h_part) {
    const int b = blockIdx.x;
    if (b >= 4 * (*nAp)) return;
    const int e = aidx[b >> 2];
    const int dr = b & 3;
    const int tid = threadIdx.x;
    const int wid = tid >> 6, lane = tid & 63;
    const int dsub = wid >> 2, fq = wid & 3;

    __shared__ __align__(16) uint_t lds_u[16384];  // 64 KB

    {   // stage xT rows [dr*512,+512) fp32 -> bf16 packed (16 KB), linear
        const float4* src = reinterpret_cast<const float4*>(xT + (size_t)dr * 512 * T_TOK);
        uint2* dst = reinterpret_cast<uint2*>(lds_u);
#pragma unroll
        for (int i = 0; i < 2; ++i) {
            const float4 v = src[tid * 2 + i];
            dst[tid * 2 + i] = make_uint2(pk2(v.x, v.y), pk2(v.z, v.w));
        }
    }
    __syncthreads();

    float acc0[16] = {}, acc1[16] = {}, acc2[16] = {}, acc3[16] = {};

    const f32x4* wrow = reinterpret_cast<const f32x4*>(
        Wu + (size_t)e * ((size_t)DHID * FINT)
           + (size_t)(dr * 512 + dsub * 128) * FINT + fq * 256 + lane * 4);
    const size_t WSTEP = FINT / 4;
    const uint4* xqw = reinterpret_cast<const uint4*>(lds_u) + (size_t)dsub * 256;

    f32x4 b0 = LDW(0), b1 = LDW(1), b2 = LDW(2), b3 = LDW(3);
    for (int j = 0; j < 128; j += 4) {
        const bool pf = (j < 124);
        STEP(j + 0, b0) if (pf) b0 = LDW(j + 4);
        STEP(j + 1, b1) if (pf) b1 = LDW(j + 5);
        STEP(j + 2, b2) if (pf) b2 = LDW(j + 6);
        STEP(j + 3, b3) if (pf) b3 = LDW(j + 7);
    }

    // 4 -> 1 over dsub, per fq (regions 0..7, then 0..3)
    __syncthreads();
    if (dsub >= 2) RW(fq * 2 + dsub - 2)
    __syncthreads();
    if (dsub < 2) RR(fq * 2 + dsub)
    __syncthreads();
    if (dsub == 1) RW(fq)
    __syncthreads();
    if (dsub == 0) {
        RR(fq)
        uint4* hp = reinterpret_cast<uint4*>(
            h_part + ((size_t)(dr * NEXP + e) * FINT + fq * 256 + lane * 4) * T_TOK);
        uint4 o;
#define ST_COL(A, k0)                                                        \
        o.x = pk2(A[0], A[1]);   o.y = pk2(A[2], A[3]);                      \
        o.z = pk2(A[4], A[5]);   o.w = pk2(A[6], A[7]);                      \
        hp[k0] = o;                                                          \
        o.x = pk2(A[8], A[9]);   o.y = pk2(A[10], A[11]);                    \
        o.z = pk2(A[12], A[13]); o.w = pk2(A[14], A[15]);                    \
        hp[k0 + 1] = o;
        ST_COL(acc0, 0) ST_COL(acc1, 2) ST_COL(acc2, 4) ST_COL(acc3, 6)
#undef ST_COL
    }
}

// ---------------------------------------------------------------------------
// K3: a[e][f][t] (bf16) = route[e][t] * relu(sum_dr h_part)^2
// Unconditional over all e (inactive e produce junk never consumed).
// ---------------------------------------------------------------------------
__global__ void k_act(const ushort_t* __restrict__ h_part, const float* __restrict__ route,
                      ushort_t* __restrict__ a_buf) {
    const int e = blockIdx.y;
    const int i = blockIdx.x * 256 + threadIdx.x;     // [0, 2048)
    const size_t base = (size_t)e * (FINT * T_TOK) + (size_t)i * 8;

    float s[8] = {};
#pragma unroll
    for (int dr = 0; dr < 4; ++dr) {
        const uint4 hv = *reinterpret_cast<const uint4*>(h_part + dr * HPART_STRIDE + base);
        s[0] += bf_lo(hv.x); s[1] += bf_hi(hv.x);
        s[2] += bf_lo(hv.y); s[3] += bf_hi(hv.y);
        s[4] += bf_lo(hv.z); s[5] += bf_hi(hv.z);
        s[6] += bf_lo(hv.w); s[7] += bf_hi(hv.w);
    }
    const int t0 = (i & 1) * 8;
    const float* r = route + e * T_TOK + t0;
    uint4 o;
    float h0, h1;
    h0 = fmaxf(s[0], 0.f); h1 = fmaxf(s[1], 0.f);
    o.x = pk2(r[0] * h0 * h0, r[1] * h1 * h1);
    h0 = fmaxf(s[2], 0.f); h1 = fmaxf(s[3], 0.f);
    o.y = pk2(r[2] * h0 * h0, r[3] * h1 * h1);
    h0 = fmaxf(s[4], 0.f); h1 = fmaxf(s[5], 0.f);
    o.z = pk2(r[4] * h0 * h0, r[5] * h1 * h1);
    h0 = fmaxf(s[6], 0.f); h1 = fmaxf(s[7], 0.f);
    o.w = pk2(r[6] * h0 * h0, r[7] * h1 * h1);
    *reinterpret_cast<uint4*>(a_buf + base) = o;
}

// ---------------------------------------------------------------------------
// K4: down-proj partials. Block=(active e, f-range fr of 256 rows) -> reads a
// CONTIGUOUS 2 MB weight slab. Waves (fs=wid>>3, dq=wid&7): rows
// [fr*256+fs*128,+128), d-slice dq (lane owns 4 d). 2->1 fs tree.
// out_part[e][fr][t][d] (bf16) = sum_{f in fr} a[e][f][t]*Wd[e][f][d]
// ---------------------------------------------------------------------------
__global__ __launch_bounds__(1024, 4) void k_down(
    const ushort_t* __restrict__ a_buf, const float* __restrict__ Wd,
    const int* __restrict__ aidx, const int* __restrict__ nAp,
    ushort_t* __restrict__ out_part) {
    const int b = blockIdx.x;
    if (b >= 4 * (*nAp)) return;
    const int e = aidx[b >> 2];
    const int fr = b & 3;
    const int tid = threadIdx.x;
    const int wid = tid >> 6, lane = tid & 63;
    const int fs = wid >> 3, dq = wid & 7;

    __shared__ __align__(16) uint_t lds_u[16384];  // 64 KB

    {   // stage a[e] rows [fr*256,+256) bf16 (8 KB), linear
        const uint4* src = reinterpret_cast<const uint4*>(
            a_buf + ((size_t)e * FINT + fr * 256) * T_TOK);
        reinterpret_cast<uint4*>(lds_u)[tid] = src[tid];
    }
    __syncthreads();

    float acc0[16] = {}, acc1[16] = {}, acc2[16] = {}, acc3[16] = {};

    const int d0 = dq * 256 + lane * 4;
    const f32x4* wrow = reinterpret_cast<const f32x4*>(
        Wd + (size_t)e * ((size_t)FINT * DHID)
           + (size_t)(fr * 256 + fs * 128) * DHID + d0);
    const size_t WSTEP = DHID / 4;
    const uint4* xqw = reinterpret_cast<const uint4*>(lds_u) + (size_t)fs * 256;

    f32x4 b0 = LDW(0), b1 = LDW(1), b2 = LDW(2), b3 = LDW(3);
    for (int j = 0; j < 128; j += 4) {
        const bool pf = (j < 124);
        STEP(j + 0, b0) if (pf) b0 = LDW(j + 4);
        STEP(j + 1, b1) if (pf) b1 = LDW(j + 5);
        STEP(j + 2, b2) if (pf) b2 = LDW(j + 6);
        STEP(j + 3, b3) if (pf) b3 = LDW(j + 7);
    }

    // 2 -> 1 over fs, per dq (regions 0..7)
    __syncthreads();
    if (fs == 1) RW(dq)
    __syncthreads();
    if (fs == 0) {
        RR(dq)
        ushort_t* op = out_part + ((size_t)(e * 4 + fr) * T_TOK) * DHID + d0;
#pragma unroll
        for (int t = 0; t < 16; ++t) {
            uint2 u;
            u.x = pk2(acc0[t], acc1[t]);
            u.y = pk2(acc2[t], acc3[t]);
            *reinterpret_cast<uint2*>(op + (size_t)t * DHID) = u;
        }
    }
}

// ---------------------------------------------------------------------------
// K5: out[t][d] = sum over active e, fr of out_part. Overwrites d_out.
// ---------------------------------------------------------------------------
__global__ void k_comb(const ushort_t* __restrict__ out_part, const int* __restrict__ aidx,
                       const int* __restrict__ nAp, float* __restrict__ out) {
    const int i = blockIdx.x * 256 + threadIdx.x;  // [0, T*D/4)
    const int nA = *nAp;
    const int t = i >> 9;
    const int d = (i & 511) * 4;
    const size_t off = (size_t)t * DHID + d;
    float s0 = 0.f, s1 = 0.f, s2 = 0.f, s3 = 0.f;
    for (int a = 0; a < nA; ++a) {
        const int e = aidx[a];
#pragma unroll
        for (int fr = 0; fr < 4; ++fr) {
            const uint2 v = *reinterpret_cast<const uint2*>(
                out_part + (size_t)(e * 4 + fr) * (T_TOK * DHID) + off);
            s0 += bf_lo(v.x); s1 += bf_hi(v.x);
            s2 += bf_lo(v.y); s3 += bf_hi(v.y);
        }
    }
    *reinterpret_cast<float4*>(out + off) = make_float4(s0, s1, s2, s3);
}

// ---------------------------------------------------------------------------
extern "C" void kernel_launch(void* const* d_in, const int* in_sizes, int n_in,
                              void* d_out, int out_size, void* d_ws, size_t ws_size,
                              hipStream_t stream) {
    (void)in_sizes; (void)n_in; (void)out_size; (void)ws_size;
    const float* x   = (const float*)d_in[0];
    const int*   idx = (const int*)d_in[1];
    const float* w   = (const float*)d_in[2];
    const float* Wu  = (const float*)d_in[3];
    const float* Wd  = (const float*)d_in[4];
    float* out = (float*)d_out;

    char* ws = (char*)d_ws;
    float*    route    = (float*)(ws + ROUTE_OFF);
    int*      aidx     = (int*)(ws + AIDX_OFF);
    int*      nA       = (int*)(ws + NA_OFF);
    float*    xT       = (float*)(ws + XT_OFF);
    ushort_t* h_part   = (ushort_t*)(ws + HPART_OFF);
    ushort_t* a_buf    = (ushort_t*)(ws + ABUF_OFF);
    ushort_t* out_part = (ushort_t*)(ws + OPART_OFF);

    k_prep<<<DHID / 64, 256, 0, stream>>>(x, idx, w, xT, route, aidx, nA);
    k_up<<<4 * NEXP, 1024, 0, stream>>>(xT, Wu, aidx, nA, h_part);
    k_act<<<dim3(8, NEXP), 256, 0, stream>>>(h_part, route, a_buf);
    k_down<<<4 * NEXP, 1024, 0, stream>>>(a_buf, Wd, aidx, nA, out_part);
    k_comb<<<(T_TOK * DHID / 4) / 256, 256, 0, stream>>>(out_part, aidx, nA, out);
}